// Round 1
// baseline (1055.714 us; speedup 1.0000x reference)
//
#include <hip/hip_runtime.h>

#define N_NODES 100000
#define N_EDGES 1600000

// ---------------- CSR build ----------------

__global__ void init_n_kernel(float* __restrict__ deg, int* __restrict__ cnt,
                              int* __restrict__ fill, int n) {
    int i = blockIdx.x * blockDim.x + threadIdx.x;
    if (i < n) { deg[i] = 1.0f; cnt[i] = 0; fill[i] = 0; }  // deg starts at self-loop weight 1
}

__global__ void edge_pass1_kernel(const int* __restrict__ dst, const float* __restrict__ w,
                                  float* __restrict__ deg, int* __restrict__ cnt, int E) {
    int e = blockIdx.x * blockDim.x + threadIdx.x;
    if (e < E) {
        int d = dst[e];
        atomicAdd(&deg[d], w[e]);
        atomicAdd(&cnt[d], 1);
    }
}

__global__ void dinv_kernel(float* __restrict__ deg, int n) {
    int i = blockIdx.x * blockDim.x + threadIdx.x;
    if (i < n) deg[i] = rsqrtf(deg[i]);  // deg >= 1 always (self-loop), safe
}

// single-block exclusive scan over cnt[0..n) -> rowptr[0..n]
__global__ __launch_bounds__(1024) void scan_kernel(const int* __restrict__ cnt,
                                                    int* __restrict__ rowptr, int n) {
    __shared__ int sums[1024];
    int tid = threadIdx.x;
    int chunk = (n + 1023) >> 10;
    int begin = tid * chunk;
    int end = min(begin + chunk, n);
    int s = 0;
    for (int i = begin; i < end; i++) s += cnt[i];
    sums[tid] = s;
    __syncthreads();
    for (int off = 1; off < 1024; off <<= 1) {
        int v = sums[tid];
        int u = (tid >= off) ? sums[tid - off] : 0;
        __syncthreads();
        sums[tid] = v + u;
        __syncthreads();
    }
    int base = (tid == 0) ? 0 : sums[tid - 1];
    for (int i = begin; i < end; i++) {
        rowptr[i] = base;
        base += cnt[i];
    }
    if (tid == 1023) rowptr[n] = sums[1023];
}

__global__ void place_kernel(const int* __restrict__ src, const int* __restrict__ dst,
                             const float* __restrict__ w, const float* __restrict__ dinv,
                             const int* __restrict__ rowptr, int* __restrict__ fill,
                             int* __restrict__ srcs, float* __restrict__ norms, int E) {
    int e = blockIdx.x * blockDim.x + threadIdx.x;
    if (e < E) {
        int s = src[e], d = dst[e];
        int pos = rowptr[d] + atomicAdd(&fill[d], 1);
        srcs[pos] = s;
        norms[pos] = dinv[s] * w[e] * dinv[d];
    }
}

// ---------------- GEMM: H = X @ W   (X: M x 128, W: 128 x FOUT) ----------------
// 64x64 tile per block, 256 threads, 4x4 register tile. f32 vector ALU.

__global__ __launch_bounds__(256) void gemm_kernel(const float* __restrict__ X,
                                                   const float* __restrict__ W,
                                                   float* __restrict__ H, int M, int FOUT) {
    __shared__ float sX[64 * 128];   // [r][k]  32 KB
    __shared__ float sW[128 * 64];   // [k][j]  32 KB
    int row0 = blockIdx.x * 64;
    int col0 = blockIdx.y * 64;
    int tid = threadIdx.x;

    // stage W tile (zero-padded past FOUT)
    for (int i = tid; i < 128 * 16; i += 256) {
        int k = i >> 4, c4 = i & 15;
        int j = col0 + c4 * 4;
        float4 v = make_float4(0.f, 0.f, 0.f, 0.f);
        if (j + 3 < FOUT) v = *(const float4*)&W[k * FOUT + j];
        ((float4*)sW)[i] = v;
    }
    // stage X tile (coalesced float4)
    for (int i = tid; i < 64 * 32; i += 256) {
        int r = i >> 5;
        int row = row0 + r;
        float4 v = make_float4(0.f, 0.f, 0.f, 0.f);
        if (row < M) v = *(const float4*)&X[(size_t)row * 128 + (i & 31) * 4];
        ((float4*)sX)[i] = v;
    }
    __syncthreads();

    int tx = tid & 15, ty = tid >> 4;
    float acc[4][4] = {};
    const float* xb = &sX[(ty * 4) * 128];
    #pragma unroll 4
    for (int k = 0; k < 128; k++) {
        float4 wv = ((const float4*)sW)[(k << 4) + tx];
        float x0 = xb[k];
        float x1 = xb[128 + k];
        float x2 = xb[256 + k];
        float x3 = xb[384 + k];
        acc[0][0] += x0 * wv.x; acc[0][1] += x0 * wv.y; acc[0][2] += x0 * wv.z; acc[0][3] += x0 * wv.w;
        acc[1][0] += x1 * wv.x; acc[1][1] += x1 * wv.y; acc[1][2] += x1 * wv.z; acc[1][3] += x1 * wv.w;
        acc[2][0] += x2 * wv.x; acc[2][1] += x2 * wv.y; acc[2][2] += x2 * wv.z; acc[2][3] += x2 * wv.w;
        acc[3][0] += x3 * wv.x; acc[3][1] += x3 * wv.y; acc[3][2] += x3 * wv.z; acc[3][3] += x3 * wv.w;
    }

    #pragma unroll
    for (int i2 = 0; i2 < 4; i2++) {
        int row = row0 + ty * 4 + i2;
        if (row < M) {
            int j = col0 + tx * 4;
            if (j + 3 < FOUT) {
                *(float4*)&H[(size_t)row * FOUT + j] =
                    make_float4(acc[i2][0], acc[i2][1], acc[i2][2], acc[i2][3]);
            }
        }
    }
}

// ---------------- Aggregation (gather over CSR) + self-loop + bias (+ReLU) ----------------
// one block per node, one thread per output feature

template<int FOUT, bool RELU>
__global__ void gather_kernel(const float* __restrict__ H, const int* __restrict__ rowptr,
                              const int* __restrict__ srcs, const float* __restrict__ norms,
                              const float* __restrict__ dinv, const float* __restrict__ bias,
                              float* __restrict__ out, int n) {
    int node = blockIdx.x;
    int f = threadIdx.x;
    int beg = rowptr[node], end = rowptr[node + 1];
    float acc = 0.0f;
    int e = beg;
    for (; e + 1 < end; e += 2) {
        int s0 = srcs[e], s1 = srcs[e + 1];
        float w0 = norms[e], w1 = norms[e + 1];
        float h0 = H[(size_t)s0 * FOUT + f];
        float h1 = H[(size_t)s1 * FOUT + f];
        acc += w0 * h0;
        acc += w1 * h1;
    }
    if (e < end) {
        acc += norms[e] * H[(size_t)srcs[e] * FOUT + f];
    }
    float di = dinv[node];
    acc += di * di * H[(size_t)node * FOUT + f];  // self-loop, weight 1
    acc += bias[f];
    if (RELU) acc = fmaxf(acc, 0.0f);
    out[(size_t)node * FOUT + f] = acc;
}

// ---------------- launch ----------------

extern "C" void kernel_launch(void* const* d_in, const int* in_sizes, int n_in,
                              void* d_out, int out_size, void* d_ws, size_t ws_size,
                              hipStream_t stream) {
    const float* x  = (const float*)d_in[0];
    const int*   ei = (const int*)d_in[1];
    const float* ew = (const float*)d_in[2];
    const float* W1 = (const float*)d_in[3];
    const float* b1 = (const float*)d_in[4];
    const float* W2 = (const float*)d_in[5];
    const float* b2 = (const float*)d_in[6];
    const float* W3 = (const float*)d_in[7];
    const float* b3 = (const float*)d_in[8];
    float* out = (float*)d_out;

    const int N = N_NODES, E = N_EDGES;
    const int* src = ei;
    const int* dst = ei + E;

    char* p = (char*)d_ws;
    float* deg    = (float*)p; p += 400000;           // N f32; becomes dinv in-place
    int*   cnt    = (int*)p;   p += 400000;           // N i32
    int*   fill   = (int*)p;   p += 400000;           // N i32
    int*   rowptr = (int*)p;   p += 400016;           // N+1 i32 (padded)
    int*   srcs   = (int*)p;   p += 6400000;          // E i32
    float* norms  = (float*)p; p += 6400000;          // E f32
    float* A      = (float*)p; p += (size_t)N * 128 * 4;  // h buffer
    float* B      = (float*)p;                        // layer output buffer

    int nb = (N + 255) / 256;
    int eb = (E + 255) / 256;

    init_n_kernel<<<nb, 256, 0, stream>>>(deg, cnt, fill, N);
    edge_pass1_kernel<<<eb, 256, 0, stream>>>(dst, ew, deg, cnt, E);
    dinv_kernel<<<nb, 256, 0, stream>>>(deg, N);
    scan_kernel<<<1, 1024, 0, stream>>>(cnt, rowptr, N);
    place_kernel<<<eb, 256, 0, stream>>>(src, dst, ew, deg, rowptr, fill, srcs, norms, E);

    int rt = (N + 63) / 64;
    dim3 g128(rt, 2);  // 128 output cols = 2 col tiles
    dim3 g40(rt, 1);   // 40 output cols = 1 col tile

    // layer 1: h = x@W1 -> A ; B = relu(agg(A) + self + b1)
    gemm_kernel<<<g128, 256, 0, stream>>>(x, W1, A, N, 128);
    gather_kernel<128, true><<<N, 128, 0, stream>>>(A, rowptr, srcs, norms, deg, b1, B, N);
    // layer 2
    gemm_kernel<<<g128, 256, 0, stream>>>(B, W2, A, N, 128);
    gather_kernel<128, true><<<N, 128, 0, stream>>>(A, rowptr, srcs, norms, deg, b2, B, N);
    // layer 3 (no relu) -> d_out
    gemm_kernel<<<g40, 256, 0, stream>>>(B, W3, A, N, 40);
    gather_kernel<40, false><<<N, 40, 0, stream>>>(A, rowptr, srcs, norms, deg, b3, out, N);
}

// Round 2
// 918.740 us; speedup vs baseline: 1.1491x; 1.1491x over previous
//
#include <hip/hip_runtime.h>

#define N_NODES 100000
#define N_EDGES 1600000
#define SCAN_NB ((N_NODES + 255) / 256)   // 391

// ---------------- CSR build ----------------

__global__ void init_n_kernel(float* __restrict__ deg, int* __restrict__ cnt,
                              int* __restrict__ fill, int n) {
    int i = blockIdx.x * blockDim.x + threadIdx.x;
    if (i < n) { deg[i] = 1.0f; cnt[i] = 0; fill[i] = 0; }  // deg starts at self-loop weight 1
}

__global__ void edge_pass1_kernel(const int* __restrict__ dst, const float* __restrict__ w,
                                  float* __restrict__ deg, int* __restrict__ cnt, int E) {
    int e = blockIdx.x * blockDim.x + threadIdx.x;
    if (e < E) {
        int d = dst[e];
        atomicAdd(&deg[d], w[e]);
        atomicAdd(&cnt[d], 1);
    }
}

__global__ void dinv_kernel(float* __restrict__ deg, int n) {
    int i = blockIdx.x * blockDim.x + threadIdx.x;
    if (i < n) deg[i] = rsqrtf(deg[i]);  // deg >= 1 always (self-loop), safe
}

// -------- two-level scan: partial sums -> scan partials -> local scan + offset --------

__global__ __launch_bounds__(256) void scan1_kernel(const int* __restrict__ cnt,
                                                    int* __restrict__ bsum, int n) {
    __shared__ int s[256];
    int tid = threadIdx.x;
    int i = blockIdx.x * 256 + tid;
    int v = (i < n) ? cnt[i] : 0;
    s[tid] = v;
    __syncthreads();
    #pragma unroll
    for (int off = 128; off > 0; off >>= 1) {
        if (tid < off) s[tid] += s[tid + off];
        __syncthreads();
    }
    if (tid == 0) bsum[blockIdx.x] = s[0];
}

__global__ __launch_bounds__(512) void scan2_kernel(int* __restrict__ bsum, int nb) {
    __shared__ int s[512];
    int tid = threadIdx.x;
    int v = (tid < nb) ? bsum[tid] : 0;
    s[tid] = v;
    __syncthreads();
    #pragma unroll
    for (int off = 1; off < 512; off <<= 1) {
        int t = s[tid];
        int u = (tid >= off) ? s[tid - off] : 0;
        __syncthreads();
        s[tid] = t + u;
        __syncthreads();
    }
    if (tid < nb) bsum[tid] = (tid == 0) ? 0 : s[tid - 1];  // exclusive
}

__global__ __launch_bounds__(256) void scan3_kernel(const int* __restrict__ cnt,
                                                    const int* __restrict__ bsum,
                                                    int* __restrict__ rowptr, int n) {
    __shared__ int s[256];
    int tid = threadIdx.x;
    int i = blockIdx.x * 256 + tid;
    int v = (i < n) ? cnt[i] : 0;
    s[tid] = v;
    __syncthreads();
    #pragma unroll
    for (int off = 1; off < 256; off <<= 1) {
        int t = s[tid];
        int u = (tid >= off) ? s[tid - off] : 0;
        __syncthreads();
        s[tid] = t + u;
        __syncthreads();
    }
    if (i < n) rowptr[i] = bsum[blockIdx.x] + s[tid] - v;   // exclusive
    if (i == 0) rowptr[n] = N_EDGES;                        // total is a constant
}

__global__ void place_kernel(const int* __restrict__ src, const int* __restrict__ dst,
                             const float* __restrict__ w, const float* __restrict__ dinv,
                             const int* __restrict__ rowptr, int* __restrict__ fill,
                             int* __restrict__ srcs, float* __restrict__ norms, int E) {
    int e = blockIdx.x * blockDim.x + threadIdx.x;
    if (e < E) {
        int s = src[e], d = dst[e];
        int pos = rowptr[d] + atomicAdd(&fill[d], 1);
        srcs[pos] = s;
        norms[pos] = dinv[s] * w[e] * dinv[d];
    }
}

// ---------------- GEMM: H = X @ W   (X: M x 128, W: 128 x FOUT) ----------------

__global__ __launch_bounds__(256) void gemm_kernel(const float* __restrict__ X,
                                                   const float* __restrict__ W,
                                                   float* __restrict__ H, int M, int FOUT) {
    __shared__ float sX[64 * 128];   // [r][k]  32 KB
    __shared__ float sW[128 * 64];   // [k][j]  32 KB
    int row0 = blockIdx.x * 64;
    int col0 = blockIdx.y * 64;
    int tid = threadIdx.x;

    for (int i = tid; i < 128 * 16; i += 256) {
        int k = i >> 4, c4 = i & 15;
        int j = col0 + c4 * 4;
        float4 v = make_float4(0.f, 0.f, 0.f, 0.f);
        if (j + 3 < FOUT) v = *(const float4*)&W[k * FOUT + j];
        ((float4*)sW)[i] = v;
    }
    for (int i = tid; i < 64 * 32; i += 256) {
        int r = i >> 5;
        int row = row0 + r;
        float4 v = make_float4(0.f, 0.f, 0.f, 0.f);
        if (row < M) v = *(const float4*)&X[(size_t)row * 128 + (i & 31) * 4];
        ((float4*)sX)[i] = v;
    }
    __syncthreads();

    int tx = tid & 15, ty = tid >> 4;
    float acc[4][4] = {};
    const float* xb = &sX[(ty * 4) * 128];
    #pragma unroll 4
    for (int k = 0; k < 128; k++) {
        float4 wv = ((const float4*)sW)[(k << 4) + tx];
        float x0 = xb[k];
        float x1 = xb[128 + k];
        float x2 = xb[256 + k];
        float x3 = xb[384 + k];
        acc[0][0] += x0 * wv.x; acc[0][1] += x0 * wv.y; acc[0][2] += x0 * wv.z; acc[0][3] += x0 * wv.w;
        acc[1][0] += x1 * wv.x; acc[1][1] += x1 * wv.y; acc[1][2] += x1 * wv.z; acc[1][3] += x1 * wv.w;
        acc[2][0] += x2 * wv.x; acc[2][1] += x2 * wv.y; acc[2][2] += x2 * wv.z; acc[2][3] += x2 * wv.w;
        acc[3][0] += x3 * wv.x; acc[3][1] += x3 * wv.y; acc[3][2] += x3 * wv.z; acc[3][3] += x3 * wv.w;
    }

    #pragma unroll
    for (int i2 = 0; i2 < 4; i2++) {
        int row = row0 + ty * 4 + i2;
        if (row < M) {
            int j = col0 + tx * 4;
            if (j + 3 < FOUT) {
                *(float4*)&H[(size_t)row * FOUT + j] =
                    make_float4(acc[i2][0], acc[i2][1], acc[i2][2], acc[i2][3]);
            }
        }
    }
}

// ---------------- Aggregation: one WAVE per node, float2 per lane (F=128) ----------------

template<bool RELU>
__global__ __launch_bounds__(256) void gather128_kernel(
        const float* __restrict__ H, const int* __restrict__ rowptr,
        const int* __restrict__ srcs, const float* __restrict__ norms,
        const float* __restrict__ dinv, const float* __restrict__ bias,
        float* __restrict__ out, int n) {
    int wave = threadIdx.x >> 6;
    int lane = threadIdx.x & 63;
    int node = blockIdx.x * 4 + wave;
    if (node >= n) return;
    int beg = rowptr[node], end = rowptr[node + 1];
    const float2* __restrict__ H2 = (const float2*)H;
    float2 acc = make_float2(0.f, 0.f);
    int e = beg;
    for (; e + 3 < end; e += 4) {
        int s0 = srcs[e], s1 = srcs[e + 1], s2 = srcs[e + 2], s3 = srcs[e + 3];
        float w0 = norms[e], w1 = norms[e + 1], w2 = norms[e + 2], w3 = norms[e + 3];
        float2 h0 = H2[(size_t)s0 * 64 + lane];
        float2 h1 = H2[(size_t)s1 * 64 + lane];
        float2 h2 = H2[(size_t)s2 * 64 + lane];
        float2 h3 = H2[(size_t)s3 * 64 + lane];
        acc.x += w0 * h0.x; acc.y += w0 * h0.y;
        acc.x += w1 * h1.x; acc.y += w1 * h1.y;
        acc.x += w2 * h2.x; acc.y += w2 * h2.y;
        acc.x += w3 * h3.x; acc.y += w3 * h3.y;
    }
    for (; e < end; e++) {
        float w0 = norms[e];
        float2 h0 = H2[(size_t)srcs[e] * 64 + lane];
        acc.x += w0 * h0.x; acc.y += w0 * h0.y;
    }
    float di = dinv[node];
    float sw = di * di;
    float2 hs = H2[(size_t)node * 64 + lane];
    acc.x += sw * hs.x; acc.y += sw * hs.y;
    float2 bv = ((const float2*)bias)[lane];
    acc.x += bv.x; acc.y += bv.y;
    if (RELU) { acc.x = fmaxf(acc.x, 0.f); acc.y = fmaxf(acc.y, 0.f); }
    ((float2*)out)[(size_t)node * 64 + lane] = acc;
}

// F=40: one wave per node, lanes 0..39 active (scalar)
__global__ __launch_bounds__(256) void gather40_kernel(
        const float* __restrict__ H, const int* __restrict__ rowptr,
        const int* __restrict__ srcs, const float* __restrict__ norms,
        const float* __restrict__ dinv, const float* __restrict__ bias,
        float* __restrict__ out, int n) {
    int wave = threadIdx.x >> 6;
    int lane = threadIdx.x & 63;
    int node = blockIdx.x * 4 + wave;
    if (node >= n || lane >= 40) return;
    int beg = rowptr[node], end = rowptr[node + 1];
    float acc = 0.0f;
    int e = beg;
    for (; e + 1 < end; e += 2) {
        float w0 = norms[e], w1 = norms[e + 1];
        acc += w0 * H[(size_t)srcs[e] * 40 + lane];
        acc += w1 * H[(size_t)srcs[e + 1] * 40 + lane];
    }
    if (e < end) acc += norms[e] * H[(size_t)srcs[e] * 40 + lane];
    float di = dinv[node];
    acc += di * di * H[(size_t)node * 40 + lane];
    acc += bias[lane];
    out[(size_t)node * 40 + lane] = acc;
}

// ---------------- launch ----------------

extern "C" void kernel_launch(void* const* d_in, const int* in_sizes, int n_in,
                              void* d_out, int out_size, void* d_ws, size_t ws_size,
                              hipStream_t stream) {
    const float* x  = (const float*)d_in[0];
    const int*   ei = (const int*)d_in[1];
    const float* ew = (const float*)d_in[2];
    const float* W1 = (const float*)d_in[3];
    const float* b1 = (const float*)d_in[4];
    const float* W2 = (const float*)d_in[5];
    const float* b2 = (const float*)d_in[6];
    const float* W3 = (const float*)d_in[7];
    const float* b3 = (const float*)d_in[8];
    float* out = (float*)d_out;

    const int N = N_NODES, E = N_EDGES;
    const int* src = ei;
    const int* dst = ei + E;

    char* p = (char*)d_ws;
    float* deg    = (float*)p; p += 400000;           // N f32; becomes dinv in-place
    int*   cnt    = (int*)p;   p += 400000;           // N i32
    int*   fill   = (int*)p;   p += 400000;           // N i32
    int*   rowptr = (int*)p;   p += 400016;           // N+1 i32 (padded)
    int*   bsum   = (int*)p;   p += 2048;             // scan partials (391 used)
    int*   srcs   = (int*)p;   p += 6400000;          // E i32
    float* norms  = (float*)p; p += 6400000;          // E f32
    float* A      = (float*)p; p += (size_t)N * 128 * 4;  // h buffer
    float* B      = (float*)p;                        // layer output buffer

    int nb = (N + 255) / 256;
    int eb = (E + 255) / 256;

    init_n_kernel<<<nb, 256, 0, stream>>>(deg, cnt, fill, N);
    edge_pass1_kernel<<<eb, 256, 0, stream>>>(dst, ew, deg, cnt, E);
    dinv_kernel<<<nb, 256, 0, stream>>>(deg, N);
    scan1_kernel<<<SCAN_NB, 256, 0, stream>>>(cnt, bsum, N);
    scan2_kernel<<<1, 512, 0, stream>>>(bsum, SCAN_NB);
    scan3_kernel<<<SCAN_NB, 256, 0, stream>>>(cnt, bsum, rowptr, N);
    place_kernel<<<eb, 256, 0, stream>>>(src, dst, ew, deg, rowptr, fill, srcs, norms, E);

    int rt = (N + 63) / 64;
    dim3 g128(rt, 2);
    dim3 g40(rt, 1);
    int gb = (N + 3) / 4;

    gemm_kernel<<<g128, 256, 0, stream>>>(x, W1, A, N, 128);
    gather128_kernel<true><<<gb, 256, 0, stream>>>(A, rowptr, srcs, norms, deg, b1, B, N);
    gemm_kernel<<<g128, 256, 0, stream>>>(B, W2, A, N, 128);
    gather128_kernel<true><<<gb, 256, 0, stream>>>(A, rowptr, srcs, norms, deg, b2, B, N);
    gemm_kernel<<<g40, 256, 0, stream>>>(B, W3, A, N, 40);
    gather40_kernel<<<gb, 256, 0, stream>>>(A, rowptr, srcs, norms, deg, b3, out, N);
}

// Round 3
// 826.219 us; speedup vs baseline: 1.2778x; 1.1120x over previous
//
#include <hip/hip_runtime.h>

#define N_NODES 100000
#define N_EDGES 1600000
#define SCAN_NB ((N_NODES + 255) / 256)   // 391

// ---------------- helpers ----------------

__device__ inline unsigned short f2bf(float f) {   // round-to-nearest-even
    unsigned int u = __float_as_uint(f);
    u += 0x7FFFu + ((u >> 16) & 1u);
    return (unsigned short)(u >> 16);
}

// ---------------- CSR build ----------------

__global__ void init_n_kernel(float* __restrict__ deg, int* __restrict__ cnt,
                              int* __restrict__ fill, int n) {
    int i = blockIdx.x * blockDim.x + threadIdx.x;
    if (i < n) { deg[i] = 1.0f; cnt[i] = 0; fill[i] = 0; }  // deg starts at self-loop weight 1
}

__global__ void edge_pass1_kernel(const int* __restrict__ dst, const float* __restrict__ w,
                                  float* __restrict__ deg, int* __restrict__ cnt, int E) {
    int e = blockIdx.x * blockDim.x + threadIdx.x;
    if (e < E) {
        int d = dst[e];
        atomicAdd(&deg[d], w[e]);
        atomicAdd(&cnt[d], 1);
    }
}

__global__ void dinv_kernel(float* __restrict__ deg, int n) {
    int i = blockIdx.x * blockDim.x + threadIdx.x;
    if (i < n) deg[i] = rsqrtf(deg[i]);
}

// -------- two-level scan --------

__global__ __launch_bounds__(256) void scan1_kernel(const int* __restrict__ cnt,
                                                    int* __restrict__ bsum, int n) {
    __shared__ int s[256];
    int tid = threadIdx.x;
    int i = blockIdx.x * 256 + tid;
    int v = (i < n) ? cnt[i] : 0;
    s[tid] = v;
    __syncthreads();
    #pragma unroll
    for (int off = 128; off > 0; off >>= 1) {
        if (tid < off) s[tid] += s[tid + off];
        __syncthreads();
    }
    if (tid == 0) bsum[blockIdx.x] = s[0];
}

__global__ __launch_bounds__(512) void scan2_kernel(int* __restrict__ bsum, int nb) {
    __shared__ int s[512];
    int tid = threadIdx.x;
    int v = (tid < nb) ? bsum[tid] : 0;
    s[tid] = v;
    __syncthreads();
    #pragma unroll
    for (int off = 1; off < 512; off <<= 1) {
        int t = s[tid];
        int u = (tid >= off) ? s[tid - off] : 0;
        __syncthreads();
        s[tid] = t + u;
        __syncthreads();
    }
    if (tid < nb) bsum[tid] = (tid == 0) ? 0 : s[tid - 1];
}

__global__ __launch_bounds__(256) void scan3_kernel(const int* __restrict__ cnt,
                                                    const int* __restrict__ bsum,
                                                    int* __restrict__ rowptr, int n) {
    __shared__ int s[256];
    int tid = threadIdx.x;
    int i = blockIdx.x * 256 + tid;
    int v = (i < n) ? cnt[i] : 0;
    s[tid] = v;
    __syncthreads();
    #pragma unroll
    for (int off = 1; off < 256; off <<= 1) {
        int t = s[tid];
        int u = (tid >= off) ? s[tid - off] : 0;
        __syncthreads();
        s[tid] = t + u;
        __syncthreads();
    }
    if (i < n) rowptr[i] = bsum[blockIdx.x] + s[tid] - v;
    if (i == 0) rowptr[n] = N_EDGES;
}

__global__ void place_kernel(const int* __restrict__ src, const int* __restrict__ dst,
                             const float* __restrict__ w, const float* __restrict__ dinv,
                             const int* __restrict__ rowptr, int* __restrict__ fill,
                             int* __restrict__ srcs, float* __restrict__ norms, int E) {
    int e = blockIdx.x * blockDim.x + threadIdx.x;
    if (e < E) {
        int s = src[e], d = dst[e];
        int pos = rowptr[d] + atomicAdd(&fill[d], 1);
        srcs[pos] = s;
        norms[pos] = dinv[s] * w[e] * dinv[d];
    }
}

// ---------------- GEMM: H = X @ W  (f32 compute, f32 or bf16 store) ----------------

template<bool BF16OUT>
__global__ __launch_bounds__(256) void gemm_kernel(const float* __restrict__ X,
                                                   const float* __restrict__ W,
                                                   void* __restrict__ Hout, int M, int FOUT) {
    __shared__ float sX[64 * 128];
    __shared__ float sW[128 * 64];
    int row0 = blockIdx.x * 64;
    int col0 = blockIdx.y * 64;
    int tid = threadIdx.x;

    for (int i = tid; i < 128 * 16; i += 256) {
        int k = i >> 4, c4 = i & 15;
        int j = col0 + c4 * 4;
        float4 v = make_float4(0.f, 0.f, 0.f, 0.f);
        if (j + 3 < FOUT) v = *(const float4*)&W[k * FOUT + j];
        ((float4*)sW)[i] = v;
    }
    for (int i = tid; i < 64 * 32; i += 256) {
        int r = i >> 5;
        int row = row0 + r;
        float4 v = make_float4(0.f, 0.f, 0.f, 0.f);
        if (row < M) v = *(const float4*)&X[(size_t)row * 128 + (i & 31) * 4];
        ((float4*)sX)[i] = v;
    }
    __syncthreads();

    int tx = tid & 15, ty = tid >> 4;
    float acc[4][4] = {};
    const float* xb = &sX[(ty * 4) * 128];
    #pragma unroll 4
    for (int k = 0; k < 128; k++) {
        float4 wv = ((const float4*)sW)[(k << 4) + tx];
        float x0 = xb[k];
        float x1 = xb[128 + k];
        float x2 = xb[256 + k];
        float x3 = xb[384 + k];
        acc[0][0] += x0 * wv.x; acc[0][1] += x0 * wv.y; acc[0][2] += x0 * wv.z; acc[0][3] += x0 * wv.w;
        acc[1][0] += x1 * wv.x; acc[1][1] += x1 * wv.y; acc[1][2] += x1 * wv.z; acc[1][3] += x1 * wv.w;
        acc[2][0] += x2 * wv.x; acc[2][1] += x2 * wv.y; acc[2][2] += x2 * wv.z; acc[2][3] += x2 * wv.w;
        acc[3][0] += x3 * wv.x; acc[3][1] += x3 * wv.y; acc[3][2] += x3 * wv.z; acc[3][3] += x3 * wv.w;
    }

    #pragma unroll
    for (int i2 = 0; i2 < 4; i2++) {
        int row = row0 + ty * 4 + i2;
        if (row < M) {
            int j = col0 + tx * 4;
            if (j + 3 < FOUT) {
                if (BF16OUT) {
                    unsigned short* Hb = (unsigned short*)Hout;
                    *(ushort4*)&Hb[(size_t)row * FOUT + j] =
                        make_ushort4(f2bf(acc[i2][0]), f2bf(acc[i2][1]),
                                     f2bf(acc[i2][2]), f2bf(acc[i2][3]));
                } else {
                    float* Hf = (float*)Hout;
                    *(float4*)&Hf[(size_t)row * FOUT + j] =
                        make_float4(acc[i2][0], acc[i2][1], acc[i2][2], acc[i2][3]);
                }
            }
        }
    }
}

// ---------------- Aggregation F=128, bf16 H: one wave/node, 1 dword (2 bf16) per lane ----------------

template<bool RELU>
__global__ __launch_bounds__(256) void gather128bf_kernel(
        const unsigned int* __restrict__ H,   // N x 64 dwords (bf16x2 packed)
        const int* __restrict__ rowptr,
        const int* __restrict__ srcs, const float* __restrict__ norms,
        const float* __restrict__ dinv, const float* __restrict__ bias,
        float* __restrict__ out, int n) {
    int wave = threadIdx.x >> 6;
    int lane = threadIdx.x & 63;
    int node = blockIdx.x * 4 + wave;
    if (node >= n) return;
    int beg = rowptr[node], end = rowptr[node + 1];
    float ax = 0.f, ay = 0.f;
    int e = beg;
    for (; e + 7 < end; e += 8) {
        int s[8]; float w[8]; unsigned int u[8];
        #pragma unroll
        for (int i = 0; i < 8; i++) { s[i] = srcs[e + i]; w[i] = norms[e + i]; }
        #pragma unroll
        for (int i = 0; i < 8; i++) { u[i] = H[(size_t)s[i] * 64 + lane]; }
        #pragma unroll
        for (int i = 0; i < 8; i++) {
            ax += w[i] * __uint_as_float(u[i] << 16);
            ay += w[i] * __uint_as_float(u[i] & 0xFFFF0000u);
        }
    }
    for (; e < end; e++) {
        float w0 = norms[e];
        unsigned int u = H[(size_t)srcs[e] * 64 + lane];
        ax += w0 * __uint_as_float(u << 16);
        ay += w0 * __uint_as_float(u & 0xFFFF0000u);
    }
    float di = dinv[node];
    float sw = di * di;
    unsigned int us = H[(size_t)node * 64 + lane];
    ax += sw * __uint_as_float(us << 16);
    ay += sw * __uint_as_float(us & 0xFFFF0000u);
    float2 bv = ((const float2*)bias)[lane];
    ax += bv.x; ay += bv.y;
    if (RELU) { ax = fmaxf(ax, 0.f); ay = fmaxf(ay, 0.f); }
    ((float2*)out)[(size_t)node * 64 + lane] = make_float2(ax, ay);
}

// F=40 f32 gather (layer 3, exact)
__global__ __launch_bounds__(256) void gather40_kernel(
        const float* __restrict__ H, const int* __restrict__ rowptr,
        const int* __restrict__ srcs, const float* __restrict__ norms,
        const float* __restrict__ dinv, const float* __restrict__ bias,
        float* __restrict__ out, int n) {
    int wave = threadIdx.x >> 6;
    int lane = threadIdx.x & 63;
    int node = blockIdx.x * 4 + wave;
    if (node >= n || lane >= 40) return;
    int beg = rowptr[node], end = rowptr[node + 1];
    float acc = 0.0f;
    int e = beg;
    for (; e + 1 < end; e += 2) {
        float w0 = norms[e], w1 = norms[e + 1];
        acc += w0 * H[(size_t)srcs[e] * 40 + lane];
        acc += w1 * H[(size_t)srcs[e + 1] * 40 + lane];
    }
    if (e < end) acc += norms[e] * H[(size_t)srcs[e] * 40 + lane];
    float di = dinv[node];
    acc += di * di * H[(size_t)node * 40 + lane];
    acc += bias[lane];
    out[(size_t)node * 40 + lane] = acc;
}

// ---------------- launch ----------------

extern "C" void kernel_launch(void* const* d_in, const int* in_sizes, int n_in,
                              void* d_out, int out_size, void* d_ws, size_t ws_size,
                              hipStream_t stream) {
    const float* x  = (const float*)d_in[0];
    const int*   ei = (const int*)d_in[1];
    const float* ew = (const float*)d_in[2];
    const float* W1 = (const float*)d_in[3];
    const float* b1 = (const float*)d_in[4];
    const float* W2 = (const float*)d_in[5];
    const float* b2 = (const float*)d_in[6];
    const float* W3 = (const float*)d_in[7];
    const float* b3 = (const float*)d_in[8];
    float* out = (float*)d_out;

    const int N = N_NODES, E = N_EDGES;
    const int* src = ei;
    const int* dst = ei + E;

    char* p = (char*)d_ws;
    float* deg    = (float*)p; p += 400000;
    int*   cnt    = (int*)p;   p += 400000;
    int*   fill   = (int*)p;   p += 400000;
    int*   rowptr = (int*)p;   p += 400016;
    int*   bsum   = (int*)p;   p += 2048;
    int*   srcs   = (int*)p;   p += 6400000;
    float* norms  = (float*)p; p += 6400000;
    void*  A      = (void*)p;  p += (size_t)N * 128 * 4;  // bf16 H (uses half) / f32 H3
    float* B      = (float*)p;                            // f32 layer output

    int nb = (N + 255) / 256;
    int eb = (E + 255) / 256;

    init_n_kernel<<<nb, 256, 0, stream>>>(deg, cnt, fill, N);
    edge_pass1_kernel<<<eb, 256, 0, stream>>>(dst, ew, deg, cnt, E);
    dinv_kernel<<<nb, 256, 0, stream>>>(deg, N);
    scan1_kernel<<<SCAN_NB, 256, 0, stream>>>(cnt, bsum, N);
    scan2_kernel<<<1, 512, 0, stream>>>(bsum, SCAN_NB);
    scan3_kernel<<<SCAN_NB, 256, 0, stream>>>(cnt, bsum, rowptr, N);
    place_kernel<<<eb, 256, 0, stream>>>(src, dst, ew, deg, rowptr, fill, srcs, norms, E);

    int rt = (N + 63) / 64;
    dim3 g128(rt, 2);
    dim3 g40(rt, 1);
    int gb = (N + 3) / 4;

    // layer 1: A(bf16) = x@W1 ; B = relu(agg(A) + self + b1)
    gemm_kernel<true><<<g128, 256, 0, stream>>>(x, W1, A, N, 128);
    gather128bf_kernel<true><<<gb, 256, 0, stream>>>((const unsigned int*)A, rowptr, srcs, norms, deg, b1, B, N);
    // layer 2
    gemm_kernel<true><<<g128, 256, 0, stream>>>(B, W2, A, N, 128);
    gather128bf_kernel<true><<<gb, 256, 0, stream>>>((const unsigned int*)A, rowptr, srcs, norms, deg, b2, B, N);
    // layer 3 (exact f32)
    gemm_kernel<false><<<g40, 256, 0, stream>>>(B, W3, A, N, 40);
    gather40_kernel<<<gb, 256, 0, stream>>>((const float*)A, rowptr, srcs, norms, deg, b3, out, N);
}

// Round 4
// 691.863 us; speedup vs baseline: 1.5259x; 1.1942x over previous
//
#include <hip/hip_runtime.h>

#define N_NODES 100000
#define N_EDGES 1600000
#define SCAN_NB ((N_NODES + 255) / 256)   // 391

// packed degree format: bits 63..52 = count, bits 51..0 = sum(w) in 2^-32 fixed point
#define CNT_SHIFT 52
#define WSUM_MASK ((1ULL << 52) - 1)

__device__ inline unsigned short f2bf(float f) {   // round-to-nearest-even
    unsigned int u = __float_as_uint(f);
    u += 0x7FFFu + ((u >> 16) & 1u);
    return (unsigned short)(u >> 16);
}

// ---------------- CSR build ----------------

__global__ void init_packed_kernel(unsigned long long* __restrict__ packed, int n) {
    int i = blockIdx.x * blockDim.x + threadIdx.x;
    if (i < n) packed[i] = 1ULL << 32;   // self-loop weight 1.0 in fixed point, count 0
}

// one u64 atomic per edge; old value's count field = this edge's rank within dst
__global__ void edge_pass1_kernel(const int* __restrict__ dst, const float* __restrict__ w,
                                  unsigned long long* __restrict__ packed,
                                  int* __restrict__ rank, int E) {
    int e = blockIdx.x * blockDim.x + threadIdx.x;
    if (e < E) {
        int d = dst[e];
        unsigned long long inc = (1ULL << CNT_SHIFT)
                               + (unsigned long long)((double)w[e] * 4294967296.0);
        unsigned long long old = atomicAdd(&packed[d], inc);
        rank[e] = (int)(old >> CNT_SHIFT);
    }
}

__global__ void extract_kernel(const unsigned long long* __restrict__ packed,
                               int* __restrict__ cnt, float* __restrict__ dinv, int n) {
    int i = blockIdx.x * blockDim.x + threadIdx.x;
    if (i < n) {
        unsigned long long p = packed[i];
        cnt[i] = (int)(p >> CNT_SHIFT);
        float s = (float)((double)(p & WSUM_MASK) * (1.0 / 4294967296.0));
        dinv[i] = rsqrtf(s);   // s >= 1 always
    }
}

// -------- two-level scan --------

__global__ __launch_bounds__(256) void scan1_kernel(const int* __restrict__ cnt,
                                                    int* __restrict__ bsum, int n) {
    __shared__ int s[256];
    int tid = threadIdx.x;
    int i = blockIdx.x * 256 + tid;
    int v = (i < n) ? cnt[i] : 0;
    s[tid] = v;
    __syncthreads();
    #pragma unroll
    for (int off = 128; off > 0; off >>= 1) {
        if (tid < off) s[tid] += s[tid + off];
        __syncthreads();
    }
    if (tid == 0) bsum[blockIdx.x] = s[0];
}

__global__ __launch_bounds__(512) void scan2_kernel(int* __restrict__ bsum, int nb) {
    __shared__ int s[512];
    int tid = threadIdx.x;
    int v = (tid < nb) ? bsum[tid] : 0;
    s[tid] = v;
    __syncthreads();
    #pragma unroll
    for (int off = 1; off < 512; off <<= 1) {
        int t = s[tid];
        int u = (tid >= off) ? s[tid - off] : 0;
        __syncthreads();
        s[tid] = t + u;
        __syncthreads();
    }
    if (tid < nb) bsum[tid] = (tid == 0) ? 0 : s[tid - 1];
}

__global__ __launch_bounds__(256) void scan3_kernel(const int* __restrict__ cnt,
                                                    const int* __restrict__ bsum,
                                                    int* __restrict__ rowptr, int n) {
    __shared__ int s[256];
    int tid = threadIdx.x;
    int i = blockIdx.x * 256 + tid;
    int v = (i < n) ? cnt[i] : 0;
    s[tid] = v;
    __syncthreads();
    #pragma unroll
    for (int off = 1; off < 256; off <<= 1) {
        int t = s[tid];
        int u = (tid >= off) ? s[tid - off] : 0;
        __syncthreads();
        s[tid] = t + u;
        __syncthreads();
    }
    if (i < n) rowptr[i] = bsum[blockIdx.x] + s[tid] - v;
    if (i == 0) rowptr[n] = N_EDGES;
}

// no atomics: slot = rowptr[dst] + rank (rank captured in pass1)
__global__ void place_kernel(const int* __restrict__ src, const int* __restrict__ dst,
                             const float* __restrict__ w, const float* __restrict__ dinv,
                             const int* __restrict__ rowptr, const int* __restrict__ rank,
                             int* __restrict__ srcs, float* __restrict__ norms, int E) {
    int e = blockIdx.x * blockDim.x + threadIdx.x;
    if (e < E) {
        int s = src[e], d = dst[e];
        int pos = rowptr[d] + rank[e];
        srcs[pos] = s;
        norms[pos] = dinv[s] * w[e] * dinv[d];
    }
}

// ---------------- GEMM: H = X @ W  (f32 compute, bf16 store) ----------------

__global__ __launch_bounds__(256) void gemm_kernel(const float* __restrict__ X,
                                                   const float* __restrict__ W,
                                                   unsigned short* __restrict__ Hout,
                                                   int M, int FOUT) {
    __shared__ float sX[64 * 128];
    __shared__ float sW[128 * 64];
    int row0 = blockIdx.x * 64;
    int col0 = blockIdx.y * 64;
    int tid = threadIdx.x;

    for (int i = tid; i < 128 * 16; i += 256) {
        int k = i >> 4, c4 = i & 15;
        int j = col0 + c4 * 4;
        float4 v = make_float4(0.f, 0.f, 0.f, 0.f);
        if (j + 3 < FOUT) v = *(const float4*)&W[k * FOUT + j];
        ((float4*)sW)[i] = v;
    }
    for (int i = tid; i < 64 * 32; i += 256) {
        int r = i >> 5;
        int row = row0 + r;
        float4 v = make_float4(0.f, 0.f, 0.f, 0.f);
        if (row < M) v = *(const float4*)&X[(size_t)row * 128 + (i & 31) * 4];
        ((float4*)sX)[i] = v;
    }
    __syncthreads();

    int tx = tid & 15, ty = tid >> 4;
    float acc[4][4] = {};
    const float* xb = &sX[(ty * 4) * 128];
    #pragma unroll 4
    for (int k = 0; k < 128; k++) {
        float4 wv = ((const float4*)sW)[(k << 4) + tx];
        float x0 = xb[k];
        float x1 = xb[128 + k];
        float x2 = xb[256 + k];
        float x3 = xb[384 + k];
        acc[0][0] += x0 * wv.x; acc[0][1] += x0 * wv.y; acc[0][2] += x0 * wv.z; acc[0][3] += x0 * wv.w;
        acc[1][0] += x1 * wv.x; acc[1][1] += x1 * wv.y; acc[1][2] += x1 * wv.z; acc[1][3] += x1 * wv.w;
        acc[2][0] += x2 * wv.x; acc[2][1] += x2 * wv.y; acc[2][2] += x2 * wv.z; acc[2][3] += x2 * wv.w;
        acc[3][0] += x3 * wv.x; acc[3][1] += x3 * wv.y; acc[3][2] += x3 * wv.z; acc[3][3] += x3 * wv.w;
    }

    #pragma unroll
    for (int i2 = 0; i2 < 4; i2++) {
        int row = row0 + ty * 4 + i2;
        if (row < M) {
            int j = col0 + tx * 4;
            if (j + 3 < FOUT) {
                *(ushort4*)&Hout[(size_t)row * FOUT + j] =
                    make_ushort4(f2bf(acc[i2][0]), f2bf(acc[i2][1]),
                                 f2bf(acc[i2][2]), f2bf(acc[i2][3]));
            }
        }
    }
}

// ---------------- Aggregation F=128 (bf16 H): one wave/node, 1 dword/lane ----------------

template<bool RELU>
__global__ __launch_bounds__(256) void gather128bf_kernel(
        const unsigned int* __restrict__ H,   // N x 64 dwords (bf16x2)
        const int* __restrict__ rowptr,
        const int* __restrict__ srcs, const float* __restrict__ norms,
        const float* __restrict__ dinv, const float* __restrict__ bias,
        float* __restrict__ out, int n) {
    int wave = threadIdx.x >> 6;
    int lane = threadIdx.x & 63;
    int node = blockIdx.x * 4 + wave;
    if (node >= n) return;
    int beg = rowptr[node], end = rowptr[node + 1];
    float ax = 0.f, ay = 0.f;
    int e = beg;
    for (; e + 7 < end; e += 8) {
        int s[8]; float w[8]; unsigned int u[8];
        #pragma unroll
        for (int i = 0; i < 8; i++) { s[i] = srcs[e + i]; w[i] = norms[e + i]; }
        #pragma unroll
        for (int i = 0; i < 8; i++) { u[i] = H[(size_t)s[i] * 64 + lane]; }
        #pragma unroll
        for (int i = 0; i < 8; i++) {
            ax += w[i] * __uint_as_float(u[i] << 16);
            ay += w[i] * __uint_as_float(u[i] & 0xFFFF0000u);
        }
    }
    for (; e < end; e++) {
        float w0 = norms[e];
        unsigned int u = H[(size_t)srcs[e] * 64 + lane];
        ax += w0 * __uint_as_float(u << 16);
        ay += w0 * __uint_as_float(u & 0xFFFF0000u);
    }
    float di = dinv[node];
    float sw = di * di;
    unsigned int us = H[(size_t)node * 64 + lane];
    ax += sw * __uint_as_float(us << 16);
    ay += sw * __uint_as_float(us & 0xFFFF0000u);
    float2 bv = ((const float2*)bias)[lane];
    ax += bv.x; ay += bv.y;
    if (RELU) { ax = fmaxf(ax, 0.f); ay = fmaxf(ay, 0.f); }
    ((float2*)out)[(size_t)node * 64 + lane] = make_float2(ax, ay);
}

// F=40 bf16 gather: one wave/node, lanes 0..19 read 1 dword (2 feats) each
__global__ __launch_bounds__(256) void gather40bf_kernel(
        const unsigned int* __restrict__ H,   // N x 20 dwords (bf16x2)
        const int* __restrict__ rowptr,
        const int* __restrict__ srcs, const float* __restrict__ norms,
        const float* __restrict__ dinv, const float* __restrict__ bias,
        float* __restrict__ out, int n) {
    int wave = threadIdx.x >> 6;
    int lane = threadIdx.x & 63;
    int node = blockIdx.x * 4 + wave;
    if (node >= n || lane >= 20) return;
    int beg = rowptr[node], end = rowptr[node + 1];
    float ax = 0.f, ay = 0.f;
    int e = beg;
    for (; e + 3 < end; e += 4) {
        int s0 = srcs[e], s1 = srcs[e + 1], s2 = srcs[e + 2], s3 = srcs[e + 3];
        float w0 = norms[e], w1 = norms[e + 1], w2 = norms[e + 2], w3 = norms[e + 3];
        unsigned int u0 = H[(size_t)s0 * 20 + lane];
        unsigned int u1 = H[(size_t)s1 * 20 + lane];
        unsigned int u2 = H[(size_t)s2 * 20 + lane];
        unsigned int u3 = H[(size_t)s3 * 20 + lane];
        ax += w0 * __uint_as_float(u0 << 16); ay += w0 * __uint_as_float(u0 & 0xFFFF0000u);
        ax += w1 * __uint_as_float(u1 << 16); ay += w1 * __uint_as_float(u1 & 0xFFFF0000u);
        ax += w2 * __uint_as_float(u2 << 16); ay += w2 * __uint_as_float(u2 & 0xFFFF0000u);
        ax += w3 * __uint_as_float(u3 << 16); ay += w3 * __uint_as_float(u3 & 0xFFFF0000u);
    }
    for (; e < end; e++) {
        float w0 = norms[e];
        unsigned int u = H[(size_t)srcs[e] * 20 + lane];
        ax += w0 * __uint_as_float(u << 16);
        ay += w0 * __uint_as_float(u & 0xFFFF0000u);
    }
    float di = dinv[node];
    float sw = di * di;
    unsigned int us = H[(size_t)node * 20 + lane];
    ax += sw * __uint_as_float(us << 16);
    ay += sw * __uint_as_float(us & 0xFFFF0000u);
    float2 bv = ((const float2*)bias)[lane];
    ax += bv.x; ay += bv.y;
    ((float2*)out)[(size_t)node * 20 + lane] = make_float2(ax, ay);
}

// ---------------- launch ----------------

extern "C" void kernel_launch(void* const* d_in, const int* in_sizes, int n_in,
                              void* d_out, int out_size, void* d_ws, size_t ws_size,
                              hipStream_t stream) {
    const float* x  = (const float*)d_in[0];
    const int*   ei = (const int*)d_in[1];
    const float* ew = (const float*)d_in[2];
    const float* W1 = (const float*)d_in[3];
    const float* b1 = (const float*)d_in[4];
    const float* W2 = (const float*)d_in[5];
    const float* b2 = (const float*)d_in[6];
    const float* W3 = (const float*)d_in[7];
    const float* b3 = (const float*)d_in[8];
    float* out = (float*)d_out;

    const int N = N_NODES, E = N_EDGES;
    const int* src = ei;
    const int* dst = ei + E;

    char* p = (char*)d_ws;
    unsigned long long* packed = (unsigned long long*)p; p += 800000;   // N u64
    float* dinv   = (float*)p; p += 400000;
    int*   cnt    = (int*)p;   p += 400000;
    int*   rowptr = (int*)p;   p += 400016;
    int*   bsum   = (int*)p;   p += 2048;
    int*   rank   = (int*)p;   p += 6400000;          // E i32
    int*   srcs   = (int*)p;   p += 6400000;          // E i32
    float* norms  = (float*)p; p += 6400000;          // E f32
    void*  A      = (void*)p;  p += (size_t)N * 128 * 2;  // bf16 H
    float* B      = (float*)p;                            // f32 layer output

    int nb = (N + 255) / 256;
    int eb = (E + 255) / 256;

    init_packed_kernel<<<nb, 256, 0, stream>>>(packed, N);
    edge_pass1_kernel<<<eb, 256, 0, stream>>>(dst, ew, packed, rank, E);
    extract_kernel<<<nb, 256, 0, stream>>>(packed, cnt, dinv, N);
    scan1_kernel<<<SCAN_NB, 256, 0, stream>>>(cnt, bsum, N);
    scan2_kernel<<<1, 512, 0, stream>>>(bsum, SCAN_NB);
    scan3_kernel<<<SCAN_NB, 256, 0, stream>>>(cnt, bsum, rowptr, N);
    place_kernel<<<eb, 256, 0, stream>>>(src, dst, ew, dinv, rowptr, rank, srcs, norms, E);

    int rt = (N + 63) / 64;
    dim3 g128(rt, 2);
    dim3 g40(rt, 1);
    int gb = (N + 3) / 4;

    gemm_kernel<<<g128, 256, 0, stream>>>(x, W1, (unsigned short*)A, N, 128);
    gather128bf_kernel<true><<<gb, 256, 0, stream>>>((const unsigned int*)A, rowptr, srcs, norms, dinv, b1, B, N);
    gemm_kernel<<<g128, 256, 0, stream>>>(B, W2, (unsigned short*)A, N, 128);
    gather128bf_kernel<true><<<gb, 256, 0, stream>>>((const unsigned int*)A, rowptr, srcs, norms, dinv, b2, B, N);
    gemm_kernel<<<g40, 256, 0, stream>>>(B, W3, (unsigned short*)A, N, 40);
    gather40bf_kernel<<<gb, 256, 0, stream>>>((const unsigned int*)A, rowptr, srcs, norms, dinv, b3, out, N);
}